// Round 1
// baseline (33.988 us; speedup 1.0000x reference)
//
#include <hip/hip_runtime.h>

// ToChoices: out[b,h,w,s,c] = (shuffle_indices[b,s] ? reals : fakes)[b,h,w,c]
// Shapes: reals/fakes (64,256,256,3) f32, shuffle_indices (64,2) int,
// out (64,256,256,2,3) f32.
//
// Memory-bound gather/interleave. One thread per pixel PAIR:
//   - writes 12 floats (48 B, 16B-aligned -> 3x float4 stores)
//   - reads 6 floats from each selected source (8B-aligned -> 3x float2 loads)

#define BB 64
#define HH 256
#define WW 256
#define HW (HH * WW)          // 65536 pixels per image
#define PAIRS_PER_B (HW / 2)  // 32768 pixel pairs per image

__global__ __launch_bounds__(256) void tochoices_kernel(
    const float* __restrict__ reals,
    const float* __restrict__ fakes,
    const int* __restrict__ idx,
    float* __restrict__ out)
{
    int t = blockIdx.x * blockDim.x + threadIdx.x;   // pair index, < 2,097,152
    int b  = t >> 15;              // t / PAIRS_PER_B
    int rp = t & (PAIRS_PER_B - 1);

    // choice index 0 = fakes, 1 = reals
    const float* s0 = idx[b * 2 + 0] ? reals : fakes;
    const float* s1 = idx[b * 2 + 1] ? reals : fakes;

    int pb = b * HW + rp * 2;      // first pixel of the pair (max ~4.2M, fits int)

    // 6 contiguous floats per source: channels of pixels pb, pb+1.
    // Byte offset pb*12 is a multiple of 24 (pb even) -> 8B aligned.
    const float2* p0 = (const float2*)(s0 + pb * 3);
    const float2* p1 = (const float2*)(s1 + pb * 3);
    float2 a01 = p0[0], a23 = p0[1], a45 = p0[2];  // a0..a5 from source for slot 0
    float2 b01 = p1[0], b23 = p1[1], b45 = p1[2];  // b0..b5 from source for slot 1

    // Output order per pair: a0 a1 a2 | b0 b1 b2 | a3 a4 a5 | b3 b4 b5
    // Base byte offset = (b*HW*6 + rp*12)*4 = multiple of 48 -> 16B aligned.
    float4* o = (float4*)(out + b * (HW * 6) + rp * 12);
    o[0] = make_float4(a01.x, a01.y, a23.x, b01.x);
    o[1] = make_float4(b01.y, b23.x, a23.y, a45.x);
    o[2] = make_float4(a45.y, b23.y, b45.x, b45.y);
}

extern "C" void kernel_launch(void* const* d_in, const int* in_sizes, int n_in,
                              void* d_out, int out_size, void* d_ws, size_t ws_size,
                              hipStream_t stream) {
    const float* reals = (const float*)d_in[0];
    const float* fakes = (const float*)d_in[1];
    const int*   idx   = (const int*)d_in[2];
    float* out = (float*)d_out;

    const int total_pairs = BB * PAIRS_PER_B;      // 2,097,152
    const int block = 256;
    const int grid = total_pairs / block;          // 8192
    tochoices_kernel<<<grid, block, 0, stream>>>(reals, fakes, idx, out);
}